// Round 5
// baseline (223.808 us; speedup 1.0000x reference)
//
#include <hip/hip_runtime.h>
#include <hip/hip_bf16.h>

typedef __attribute__((ext_vector_type(8))) short bf16x8;
typedef __attribute__((ext_vector_type(16))) float f32x16;

#define DHEAD 64
#define L_SEQ 2048
// softmax scale 1/8 folded with log2(e): exp(x/8) == exp2(x*QSCALE)
#define QSCALE (0.125f * 1.44269504088896340736f)

union U4S8 { uint4 u; bf16x8 s; };

__device__ __forceinline__ unsigned pk2(float a, float b) {
    union { __hip_bfloat162 h; unsigned u; } v;
    v.h = __float22bfloat162_rn(make_float2(a, b));
    return v.u;
}

__device__ __forceinline__ float fexp2(float x) {
#if __has_builtin(__builtin_amdgcn_exp2f)
    return __builtin_amdgcn_exp2f(x);
#else
    return __expf(x * 0.69314718055994530942f);
#endif
}

__device__ __forceinline__ float max16(const float* p) {   // depth-4 tree
    float a0 = fmaxf(p[0],  p[1]),  a1 = fmaxf(p[2],  p[3]);
    float a2 = fmaxf(p[4],  p[5]),  a3 = fmaxf(p[6],  p[7]);
    float a4 = fmaxf(p[8],  p[9]),  a5 = fmaxf(p[10], p[11]);
    float a6 = fmaxf(p[12], p[13]), a7 = fmaxf(p[14], p[15]);
    float b0 = fmaxf(a0, a1), b1 = fmaxf(a2, a3);
    float b2 = fmaxf(a4, a5), b3 = fmaxf(a6, a7);
    return fmaxf(fmaxf(b0, b1), fmaxf(b2, b3));
}
__device__ __forceinline__ float sum16(const float* p) {   // depth-4 tree
    float a0 = p[0] + p[1],   a1 = p[2] + p[3];
    float a2 = p[4] + p[5],   a3 = p[6] + p[7];
    float a4 = p[8] + p[9],   a5 = p[10] + p[11];
    float a6 = p[12] + p[13], a7 = p[14] + p[15];
    float b0 = a0 + a1, b1 = a2 + a3, b2 = a4 + a5, b3 = a6 + a7;
    return (b0 + b1) + (b2 + b3);
}

// LDS layouts (per buffer, 16 chunks x 64 slots x 16B = 16KB each K and V):
//  K chunk kb*4+kc, slot l: K[kb*32+(l&31)][kc*16+8*(l>>5)+j]   (A-frag order)
//  V chunk kc*2+dt, slot l: V[kc*16+8*(l>>5)+j][dt*32+(l&31)]   (B-frag order)
// Every ds_read AND ds_write is chunk_base + lane*16B => conflict-free.

__global__ __launch_bounds__(256, 2)
void fattn_kernel(const float* __restrict__ Qg, const float* __restrict__ Kg,
                  const float* __restrict__ Vg, float* __restrict__ Og) {
    __shared__ uint4 sK4[2][16][64];
    __shared__ uint4 sV4[2][16][64];

    const int tid  = threadIdx.x;
    const int lane = tid & 63;
    const int w    = tid >> 6;
    const int hi   = lane >> 5;
    const int c    = lane & 31;

    // Block decode: 512 blocks = 32 bh x 8 pairs x 2 halves.
    // Waves 0,1 -> q-tile pr (light); waves 2,3 -> q-tile 15-pr (heavy); shared K/V stage.
    // Blocks id and id+256 are the two halves of the SAME (bh, pair): equal duration,
    // same K/V stream (L2/L1 sharing). Every block has chunk-work == 17 tile-units.
    const int id = blockIdx.x;
    const int bh = (id & 7) + 8 * ((id >> 3) & 3);
    const int r_ = id >> 5;            // 0..15
    const int pr = r_ & 7;             // pair index 0..7
    const int h  = r_ >> 3;            // half 0/1

    const size_t base = (size_t)bh * L_SEQ * DHEAD;
    const int Tw   = (w < 2) ? pr : (15 - pr);   // this wave's q-tile
    const int nt   = 16 - pr;                    // KV tiles this block stages
    const int off  = 64 * h + 32 * (w & 1);      // row offset within the q-tile
    const int q0w  = Tw * 128 + off;             // this wave's 32 q-rows
    const int nkbD = (off >> 5) + 1;             // live 32-key blocks on diagonal tile

    // ---- Q fragments (B-operand), scale folded ----
    bf16x8 qf[4];
    {
        const float* Qrow = Qg + base + (size_t)(q0w + c) * DHEAD;
        #pragma unroll
        for (int kc = 0; kc < 4; ++kc) {
            float4 aa = *(const float4*)(Qrow + kc * 16 + hi * 8);
            float4 bb = *(const float4*)(Qrow + kc * 16 + hi * 8 + 4);
            U4S8 t;
            t.u = make_uint4(pk2(aa.x * QSCALE, aa.y * QSCALE),
                             pk2(aa.z * QSCALE, aa.w * QSCALE),
                             pk2(bb.x * QSCALE, bb.y * QSCALE),
                             pk2(bb.z * QSCALE, bb.w * QSCALE));
            qf[kc] = t.s;
        }
    }

    // ---- staging: thread (w,hi,c) ----
    const float* Kpb = Kg + base + (size_t)(32 * w + c) * DHEAD + 32 * hi;
    const float* Vpb = Vg + base + (size_t)(32 * w + 16 * hi) * DHEAD + c;

    float4 rk[8];
    float  rv[32];

    auto load_tile = [&](int kt) {
        const float* Kp = Kpb + (size_t)kt * 128 * DHEAD;
        #pragma unroll
        for (int t = 0; t < 8; ++t) rk[t] = *(const float4*)(Kp + 4 * t);
        const float* Vp = Vpb + (size_t)kt * 128 * DHEAD;
        #pragma unroll
        for (int j = 0; j < 16; ++j) {
            rv[j]      = Vp[j * DHEAD];
            rv[16 + j] = Vp[j * DHEAD + 32];
        }
    };

    auto write_tile = [&](int nb) {
        #pragma unroll
        for (int q = 0; q < 2; ++q)
            #pragma unroll
            for (int hh = 0; hh < 2; ++hh) {
                const float4 r0 = rk[4 * q + 2 * hh], r1 = rk[4 * q + 2 * hh + 1];
                sK4[nb][w * 4 + 2 * hi + q][hh * 32 + c] =
                    make_uint4(pk2(r0.x, r0.y), pk2(r0.z, r0.w),
                               pk2(r1.x, r1.y), pk2(r1.z, r1.w));
            }
        #pragma unroll
        for (int dt = 0; dt < 2; ++dt)
            #pragma unroll
            for (int hh = 0; hh < 2; ++hh) {
                const int b = 16 * dt + 8 * hh;
                sV4[nb][(2 * w + hi) * 2 + dt][hh * 32 + c] =
                    make_uint4(pk2(rv[b + 0], rv[b + 1]), pk2(rv[b + 2], rv[b + 3]),
                               pk2(rv[b + 4], rv[b + 5]), pk2(rv[b + 6], rv[b + 7]));
            }
    };

    f32x16 o0e = {0,0,0,0,0,0,0,0,0,0,0,0,0,0,0,0};
    f32x16 o0o = o0e, o1e = o0e, o1o = o0e;
    float m_r = -1e30f, l_r = 0.f;

    load_tile(0);
    write_tile(0);
    __syncthreads();

    for (int kt = 0; kt < nt; ++kt) {
        const int  cur = kt & 1;
        const bool pf  = (kt + 1 < nt);
        if (pf) load_tile(kt + 1);          // issue-early (T14)

        if (kt <= Tw) {
            const bool diag = (kt == Tw);
            const int  nkb  = diag ? nkbD : 4;

            float p[4][16];

            // ---- S^T = K * Q^T ----
            __builtin_amdgcn_s_setprio(1);
            #pragma unroll
            for (int kb = 0; kb < 4; ++kb) {
                if (kb < nkb) {
                    f32x16 s = {0,0,0,0,0,0,0,0,0,0,0,0,0,0,0,0};
                    #pragma unroll
                    for (int kc = 0; kc < 4; ++kc) {
                        U4S8 t; t.u = sK4[cur][kb * 4 + kc][lane];
                        s = __builtin_amdgcn_mfma_f32_32x32x16_bf16(t.s, qf[kc], s, 0, 0, 0);
                    }
                    #pragma unroll
                    for (int r = 0; r < 16; ++r) p[kb][r] = s[r];
                }
            }
            __builtin_amdgcn_s_setprio(0);

            if (diag) {     // mask this wave's own diagonal 32x32 (kb == nkbD-1)
                #pragma unroll
                for (int r = 0; r < 16; ++r) {
                    const int kk = (r & 3) + 8 * (r >> 2) + 4 * hi;
                    if (kk > c) p[nkbD - 1][r] = -1e30f;
                }
            }

            // ---- online softmax (tree-reduced, exp2 domain) ----
            float mx = max16(p[0]);
            if (nkb > 1) {
                float mxb = (nkb > 2) ? fmaxf(max16(p[1]),
                                              (nkb > 3) ? fmaxf(max16(p[2]), max16(p[3]))
                                                        : max16(p[2]))
                                      : max16(p[1]);
                mx = fmaxf(mx, mxb);
            }
            mx = fmaxf(mx, __shfl_xor(mx, 32));

            if (__any(mx > m_r + 8.f)) {    // defer-max (T13)
                const float mn    = fmaxf(m_r, mx);
                const float alpha = fexp2(m_r - mn);
                m_r  = mn;
                l_r *= alpha;
                #pragma unroll
                for (int r = 0; r < 16; ++r) {
                    const float ab = __shfl(alpha, (r & 3) + 8 * (r >> 2) + 4 * hi);
                    o0e[r] *= ab; o0o[r] *= ab; o1e[r] *= ab; o1o[r] *= ab;
                }
            }

            #pragma unroll
            for (int kb = 0; kb < 4; ++kb) {
                if (kb < nkb) {
                    #pragma unroll
                    for (int r = 0; r < 16; ++r) p[kb][r] = fexp2(p[kb][r] - m_r);
                }
            }
            float rs = sum16(p[0]);
            if (nkb > 1) {
                float rsb = (nkb > 2) ? ((nkb > 3) ? (sum16(p[1]) + (sum16(p[2]) + sum16(p[3])))
                                                   : (sum16(p[1]) + sum16(p[2])))
                                      : sum16(p[1]);
                rs += rsb;
            }
            rs += __shfl_xor(rs, 32);
            l_r += rs;

            // ---- P -> A-frags (in-register) + O += P V (even/odd split chains) ----
            __builtin_amdgcn_s_setprio(1);
            #pragma unroll
            for (int kc = 0; kc < 8; ++kc) {
                if (kc < 2 * nkb) {
                    const int kb = kc >> 1, bs = (kc & 1) * 8;
                    const unsigned w01 = pk2(p[kb][bs + 0], p[kb][bs + 1]);
                    const unsigned w23 = pk2(p[kb][bs + 2], p[kb][bs + 3]);
                    const unsigned w45 = pk2(p[kb][bs + 4], p[kb][bs + 5]);
                    const unsigned w67 = pk2(p[kb][bs + 6], p[kb][bs + 7]);
                    const unsigned x01 = (unsigned)__shfl_xor((int)w01, 32);
                    const unsigned x23 = (unsigned)__shfl_xor((int)w23, 32);
                    const unsigned x45 = (unsigned)__shfl_xor((int)w45, 32);
                    const unsigned x67 = (unsigned)__shfl_xor((int)w67, 32);
                    U4S8 t;
                    t.u = make_uint4(hi ? x45 : w01, hi ? x67 : w23,
                                     hi ? w45 : x01, hi ? w67 : x23);
                    U4S8 tv0; tv0.u = sV4[cur][kc * 2][lane];
                    U4S8 tv1; tv1.u = sV4[cur][kc * 2 + 1][lane];
                    if (kc & 1) {
                        o0o = __builtin_amdgcn_mfma_f32_32x32x16_bf16(t.s, tv0.s, o0o, 0, 0, 0);
                        o1o = __builtin_amdgcn_mfma_f32_32x32x16_bf16(t.s, tv1.s, o1o, 0, 0, 0);
                    } else {
                        o0e = __builtin_amdgcn_mfma_f32_32x32x16_bf16(t.s, tv0.s, o0e, 0, 0, 0);
                        o1e = __builtin_amdgcn_mfma_f32_32x32x16_bf16(t.s, tv1.s, o1e, 0, 0, 0);
                    }
                }
            }
            __builtin_amdgcn_s_setprio(0);
        }

        if (pf) write_tile(cur ^ 1);        // write-late
        __syncthreads();
    }

    // ---- epilogue: merge chains, normalize, store ----
    const float linv = 1.f / l_r;
    float* Op = Og + base;
    #pragma unroll
    for (int r = 0; r < 16; ++r) {
        const int   cr  = (r & 3) + 8 * (r >> 2) + 4 * hi;
        const float lb  = __shfl(linv, cr);
        const int   row = q0w + cr;
        Op[(size_t)row * DHEAD + c]      = (o0e[r] + o0o[r]) * lb;
        Op[(size_t)row * DHEAD + 32 + c] = (o1e[r] + o1o[r]) * lb;
    }
}

extern "C" void kernel_launch(void* const* d_in, const int* in_sizes, int n_in,
                              void* d_out, int out_size, void* d_ws, size_t ws_size,
                              hipStream_t stream) {
    const float* Q = (const float*)d_in[0];
    const float* K = (const float*)d_in[1];
    const float* V = (const float*)d_in[2];
    float* O = (float*)d_out;
    fattn_kernel<<<dim3(512), dim3(256), 0, stream>>>(Q, K, V, O);
}

// Round 6
// 220.742 us; speedup vs baseline: 1.0139x; 1.0139x over previous
//
#include <hip/hip_runtime.h>
#include <hip/hip_bf16.h>

typedef __attribute__((ext_vector_type(8))) short bf16x8;
typedef __attribute__((ext_vector_type(16))) float f32x16;

#define DHEAD 64
#define L_SEQ 2048
// softmax scale 1/8 folded with log2(e): exp(x/8) == exp2(x*QSCALE)
#define QSCALE (0.125f * 1.44269504088896340736f)

union U4S8 { uint4 u; bf16x8 s; };

__device__ __forceinline__ unsigned pk2(float a, float b) {
    union { __hip_bfloat162 h; unsigned u; } v;
    v.h = __float22bfloat162_rn(make_float2(a, b));
    return v.u;
}

__device__ __forceinline__ float fexp2(float x) {
#if __has_builtin(__builtin_amdgcn_exp2f)
    return __builtin_amdgcn_exp2f(x);
#else
    return __expf(x * 0.69314718055994530942f);
#endif
}

// Depth-4 trees, constant-index only (NO pointer passing — round-5's helper fns
// made the p array address-escape -> scratch -> 432MB of HBM scratch traffic).
#define MAX16(P) fmaxf(fmaxf(fmaxf(fmaxf(P[0],P[1]),fmaxf(P[2],P[3])),          \
                             fmaxf(fmaxf(P[4],P[5]),fmaxf(P[6],P[7]))),         \
                       fmaxf(fmaxf(fmaxf(P[8],P[9]),fmaxf(P[10],P[11])),        \
                             fmaxf(fmaxf(P[12],P[13]),fmaxf(P[14],P[15]))))
#define SUM16(P) ((((P[0]+P[1])+(P[2]+P[3]))+((P[4]+P[5])+(P[6]+P[7])))         \
                + (((P[8]+P[9])+(P[10]+P[11]))+((P[12]+P[13])+(P[14]+P[15]))))

// LDS layouts (per buffer, 16 chunks x 64 slots x 16B = 16KB each K and V):
//  K chunk kb*4+kc, slot l: K[kb*32+(l&31)][kc*16+8*(l>>5)+j]   (A-frag order)
//  V chunk kc*2+dt, slot l: V[kc*16+8*(l>>5)+j][dt*32+(l&31)]   (B-frag order)
// Every ds_read AND ds_write is chunk_base + lane*16B => conflict-free.

__global__ __launch_bounds__(256, 2)
void fattn_kernel(const float* __restrict__ Qg, const float* __restrict__ Kg,
                  const float* __restrict__ Vg, float* __restrict__ Og) {
    __shared__ uint4 sK4[2][16][64];
    __shared__ uint4 sV4[2][16][64];

    const int tid  = threadIdx.x;
    const int lane = tid & 63;
    const int w    = tid >> 6;
    const int hi   = lane >> 5;
    const int c    = lane & 31;

    // Block decode: 512 blocks = 32 bh x 8 pairs x 2 halves.
    // Waves 0,1 -> q-tile pr (light); waves 2,3 -> q-tile 15-pr (heavy); shared K/V.
    // Every block stages nt = 16-pr tiles and computes 17 tile-units total.
    const int id = blockIdx.x;
    const int bh = (id & 7) + 8 * ((id >> 3) & 3);
    const int r_ = id >> 5;            // 0..15
    const int pr = r_ & 7;             // pair index 0..7
    const int h  = r_ >> 3;            // half 0/1

    const size_t base = (size_t)bh * L_SEQ * DHEAD;
    const int Tw   = (w < 2) ? pr : (15 - pr);   // this wave's q-tile
    const int nt   = 16 - pr;                    // KV tiles this block stages
    const int off  = 64 * h + 32 * (w & 1);      // row offset within the q-tile
    const int q0w  = Tw * 128 + off;             // this wave's 32 q-rows
    const int nkbD = (off >> 5) + 1;             // live 32-key blocks on diagonal tile

    // ---- Q fragments (B-operand), scale folded ----
    bf16x8 qf[4];
    {
        const float* Qrow = Qg + base + (size_t)(q0w + c) * DHEAD;
        #pragma unroll
        for (int kc = 0; kc < 4; ++kc) {
            float4 aa = *(const float4*)(Qrow + kc * 16 + hi * 8);
            float4 bb = *(const float4*)(Qrow + kc * 16 + hi * 8 + 4);
            U4S8 t;
            t.u = make_uint4(pk2(aa.x * QSCALE, aa.y * QSCALE),
                             pk2(aa.z * QSCALE, aa.w * QSCALE),
                             pk2(bb.x * QSCALE, bb.y * QSCALE),
                             pk2(bb.z * QSCALE, bb.w * QSCALE));
            qf[kc] = t.s;
        }
    }

    // ---- staging: thread (w,hi,c) ----
    const float* Kpb = Kg + base + (size_t)(32 * w + c) * DHEAD + 32 * hi;
    const float* Vpb = Vg + base + (size_t)(32 * w + 16 * hi) * DHEAD + c;

    float4 rk[8];
    float  rv[32];

    auto load_tile = [&](int kt) {
        const float* Kp = Kpb + (size_t)kt * 128 * DHEAD;
        #pragma unroll
        for (int t = 0; t < 8; ++t) rk[t] = *(const float4*)(Kp + 4 * t);
        const float* Vp = Vpb + (size_t)kt * 128 * DHEAD;
        #pragma unroll
        for (int j = 0; j < 16; ++j) {
            rv[j]      = Vp[j * DHEAD];
            rv[16 + j] = Vp[j * DHEAD + 32];
        }
    };

    auto write_tile = [&](int nb) {
        #pragma unroll
        for (int q = 0; q < 2; ++q)
            #pragma unroll
            for (int hh = 0; hh < 2; ++hh) {
                const float4 r0 = rk[4 * q + 2 * hh], r1 = rk[4 * q + 2 * hh + 1];
                sK4[nb][w * 4 + 2 * hi + q][hh * 32 + c] =
                    make_uint4(pk2(r0.x, r0.y), pk2(r0.z, r0.w),
                               pk2(r1.x, r1.y), pk2(r1.z, r1.w));
            }
        #pragma unroll
        for (int dt = 0; dt < 2; ++dt)
            #pragma unroll
            for (int hh = 0; hh < 2; ++hh) {
                const int b = 16 * dt + 8 * hh;
                sV4[nb][(2 * w + hi) * 2 + dt][hh * 32 + c] =
                    make_uint4(pk2(rv[b + 0], rv[b + 1]), pk2(rv[b + 2], rv[b + 3]),
                               pk2(rv[b + 4], rv[b + 5]), pk2(rv[b + 6], rv[b + 7]));
            }
    };

    f32x16 o0 = {0,0,0,0,0,0,0,0,0,0,0,0,0,0,0,0};
    f32x16 o1 = o0;
    float m_r = -1e30f, l_r = 0.f;

    load_tile(0);
    write_tile(0);
    __syncthreads();

    for (int kt = 0; kt < nt; ++kt) {
        const int  cur = kt & 1;
        const bool pf  = (kt + 1 < nt);
        if (pf) load_tile(kt + 1);          // issue-early (T14)

        if (kt <= Tw) {
            const bool diag = (kt == Tw);
            const int  nkb  = diag ? nkbD : 4;

            float p[4][16];

            // ---- S^T = K * Q^T ----
            __builtin_amdgcn_s_setprio(1);
            #pragma unroll
            for (int kb = 0; kb < 4; ++kb) {
                if (kb < nkb) {
                    f32x16 s = {0,0,0,0,0,0,0,0,0,0,0,0,0,0,0,0};
                    #pragma unroll
                    for (int kc = 0; kc < 4; ++kc) {
                        U4S8 t; t.u = sK4[cur][kb * 4 + kc][lane];
                        s = __builtin_amdgcn_mfma_f32_32x32x16_bf16(t.s, qf[kc], s, 0, 0, 0);
                    }
                    #pragma unroll
                    for (int r = 0; r < 16; ++r) p[kb][r] = s[r];
                }
            }
            __builtin_amdgcn_s_setprio(0);

            if (diag) {     // mask this wave's own diagonal 32x32 (kb == nkbD-1)
                #pragma unroll
                for (int r = 0; r < 16; ++r) {
                    const int kk = (r & 3) + 8 * (r >> 2) + 4 * hi;
                    if (kk > c) p[nkbD - 1][r] = -1e30f;
                }
            }

            // ---- online softmax (depth-4 trees, exp2 domain) ----
            float mx = MAX16(p[0]);
            if (nkb > 1) {
                float mxb = (nkb > 2) ? fmaxf(MAX16(p[1]),
                                              (nkb > 3) ? fmaxf(MAX16(p[2]), MAX16(p[3]))
                                                        : MAX16(p[2]))
                                      : MAX16(p[1]);
                mx = fmaxf(mx, mxb);
            }
            mx = fmaxf(mx, __shfl_xor(mx, 32));

            if (__any(mx > m_r + 8.f)) {    // defer-max (T13)
                const float mn    = fmaxf(m_r, mx);
                const float alpha = fexp2(m_r - mn);
                m_r  = mn;
                l_r *= alpha;
                #pragma unroll
                for (int r = 0; r < 16; ++r) {
                    const float ab = __shfl(alpha, (r & 3) + 8 * (r >> 2) + 4 * hi);
                    o0[r] *= ab; o1[r] *= ab;
                }
            }

            #pragma unroll
            for (int kb = 0; kb < 4; ++kb) {
                if (kb < nkb) {
                    #pragma unroll
                    for (int r = 0; r < 16; ++r) p[kb][r] = fexp2(p[kb][r] - m_r);
                }
            }
            float rs = SUM16(p[0]);
            if (nkb > 1) {
                float rsb = (nkb > 2) ? ((nkb > 3) ? (SUM16(p[1]) + (SUM16(p[2]) + SUM16(p[3])))
                                                   : (SUM16(p[1]) + SUM16(p[2])))
                                      : SUM16(p[1]);
                rs += rsb;
            }
            rs += __shfl_xor(rs, 32);
            l_r += rs;

            // ---- P -> A-frags (in-register cross-half exchange) + O += P V ----
            __builtin_amdgcn_s_setprio(1);
            #pragma unroll
            for (int kc = 0; kc < 8; ++kc) {
                if (kc < 2 * nkb) {
                    const int kb = kc >> 1, bs = (kc & 1) * 8;
                    const unsigned w01 = pk2(p[kb][bs + 0], p[kb][bs + 1]);
                    const unsigned w23 = pk2(p[kb][bs + 2], p[kb][bs + 3]);
                    const unsigned w45 = pk2(p[kb][bs + 4], p[kb][bs + 5]);
                    const unsigned w67 = pk2(p[kb][bs + 6], p[kb][bs + 7]);
                    const unsigned x01 = (unsigned)__shfl_xor((int)w01, 32);
                    const unsigned x23 = (unsigned)__shfl_xor((int)w23, 32);
                    const unsigned x45 = (unsigned)__shfl_xor((int)w45, 32);
                    const unsigned x67 = (unsigned)__shfl_xor((int)w67, 32);
                    U4S8 t;
                    t.u = make_uint4(hi ? x45 : w01, hi ? x67 : w23,
                                     hi ? w45 : x01, hi ? w67 : x23);
                    U4S8 tv0; tv0.u = sV4[cur][kc * 2][lane];
                    o0 = __builtin_amdgcn_mfma_f32_32x32x16_bf16(t.s, tv0.s, o0, 0, 0, 0);
                    U4S8 tv1; tv1.u = sV4[cur][kc * 2 + 1][lane];
                    o1 = __builtin_amdgcn_mfma_f32_32x32x16_bf16(t.s, tv1.s, o1, 0, 0, 0);
                }
            }
            __builtin_amdgcn_s_setprio(0);
        }

        if (pf) write_tile(cur ^ 1);        // write-late
        __syncthreads();
    }

    // ---- epilogue: normalize, store ----
    const float linv = 1.f / l_r;
    float* Op = Og + base;
    #pragma unroll
    for (int r = 0; r < 16; ++r) {
        const int   cr  = (r & 3) + 8 * (r >> 2) + 4 * hi;
        const float lb  = __shfl(linv, cr);
        const int   row = q0w + cr;
        Op[(size_t)row * DHEAD + c]      = o0[r] * lb;
        Op[(size_t)row * DHEAD + 32 + c] = o1[r] * lb;
    }
}

extern "C" void kernel_launch(void* const* d_in, const int* in_sizes, int n_in,
                              void* d_out, int out_size, void* d_ws, size_t ws_size,
                              hipStream_t stream) {
    const float* Q = (const float*)d_in[0];
    const float* K = (const float*)d_in[1];
    const float* V = (const float*)d_in[2];
    float* O = (float*)d_out;
    fattn_kernel<<<dim3(512), dim3(256), 0, stream>>>(Q, K, V, O);
}

// Round 7
// 82.824 us; speedup vs baseline: 2.7022x; 2.6652x over previous
//
#include <hip/hip_runtime.h>
#include <hip/hip_bf16.h>

typedef __attribute__((ext_vector_type(8))) short bf16x8;
typedef __attribute__((ext_vector_type(16))) float f32x16;

#define DHEAD 64
#define L_SEQ 2048
// softmax scale 1/8 folded with log2(e): exp(x/8) == exp2(x*QSCALE)
#define QSCALE (0.125f * 1.44269504088896340736f)

union U4S8 { uint4 u; bf16x8 s; };

__device__ __forceinline__ unsigned pk2(float a, float b) {
    union { __hip_bfloat162 h; unsigned u; } v;
    v.h = __float22bfloat162_rn(make_float2(a, b));
    return v.u;
}

__device__ __forceinline__ float fexp2(float x) {
#if __has_builtin(__builtin_amdgcn_exp2f)
    return __builtin_amdgcn_exp2f(x);
#else
    return __expf(x * 0.69314718055994530942f);
#endif
}

// Depth-4 trees, constant-index only. NOTE (rounds 5/6 lesson, rule #20):
// p[4][16] must NEVER be indexed with a runtime value — one runtime-indexed
// store (the old p[nkbD-1][r] mask) demoted the whole array to scratch and
// cost 400+ MB of HBM scratch traffic (220us). All indices below are
// compile-time; runtime decisions are conditions only.
#define MAX16(P) fmaxf(fmaxf(fmaxf(fmaxf(P[0],P[1]),fmaxf(P[2],P[3])),          \
                             fmaxf(fmaxf(P[4],P[5]),fmaxf(P[6],P[7]))),         \
                       fmaxf(fmaxf(fmaxf(P[8],P[9]),fmaxf(P[10],P[11])),        \
                             fmaxf(fmaxf(P[12],P[13]),fmaxf(P[14],P[15]))))
#define SUM16(P) ((((P[0]+P[1])+(P[2]+P[3]))+((P[4]+P[5])+(P[6]+P[7])))         \
                + (((P[8]+P[9])+(P[10]+P[11]))+((P[12]+P[13])+(P[14]+P[15]))))

// LDS layouts (per buffer, 16 chunks x 64 slots x 16B = 16KB each K and V):
//  K chunk kb*4+kc, slot l: K[kb*32+(l&31)][kc*16+8*(l>>5)+j]   (A-frag order)
//  V chunk kc*2+dt, slot l: V[kc*16+8*(l>>5)+j][dt*32+(l&31)]   (B-frag order)
// Every ds_read AND ds_write is chunk_base + lane*16B => conflict-free.

__global__ __launch_bounds__(256, 2)
void fattn_kernel(const float* __restrict__ Qg, const float* __restrict__ Kg,
                  const float* __restrict__ Vg, float* __restrict__ Og) {
    __shared__ uint4 sK4[2][16][64];
    __shared__ uint4 sV4[2][16][64];

    const int tid  = threadIdx.x;
    const int lane = tid & 63;
    const int w    = tid >> 6;
    const int hi   = lane >> 5;
    const int c    = lane & 31;

    // Block decode: 512 blocks = 32 bh x 8 pairs x 2 halves.
    // Waves 0,1 -> q-tile pr (light); waves 2,3 -> q-tile 15-pr (heavy); shared K/V.
    // Every block stages nt = 16-pr tiles and computes 17 tile-units total.
    const int id = blockIdx.x;
    const int bh = (id & 7) + 8 * ((id >> 3) & 3);
    const int r_ = id >> 5;            // 0..15
    const int pr = r_ & 7;             // pair index 0..7
    const int h  = r_ >> 3;            // half 0/1

    const size_t base = (size_t)bh * L_SEQ * DHEAD;
    const int Tw   = (w < 2) ? pr : (15 - pr);   // this wave's q-tile
    const int nt   = 16 - pr;                    // KV tiles this block stages
    const int off  = 64 * h + 32 * (w & 1);      // row offset within the q-tile
    const int q0w  = Tw * 128 + off;             // this wave's 32 q-rows
    const int nkbD = (off >> 5) + 1;             // live 32-key blocks on diagonal tile

    // ---- Q fragments (B-operand), scale folded ----
    bf16x8 qf[4];
    {
        const float* Qrow = Qg + base + (size_t)(q0w + c) * DHEAD;
        #pragma unroll
        for (int kc = 0; kc < 4; ++kc) {
            float4 aa = *(const float4*)(Qrow + kc * 16 + hi * 8);
            float4 bb = *(const float4*)(Qrow + kc * 16 + hi * 8 + 4);
            U4S8 t;
            t.u = make_uint4(pk2(aa.x * QSCALE, aa.y * QSCALE),
                             pk2(aa.z * QSCALE, aa.w * QSCALE),
                             pk2(bb.x * QSCALE, bb.y * QSCALE),
                             pk2(bb.z * QSCALE, bb.w * QSCALE));
            qf[kc] = t.s;
        }
    }

    // ---- staging: thread (w,hi,c) ----
    const float* Kpb = Kg + base + (size_t)(32 * w + c) * DHEAD + 32 * hi;
    const float* Vpb = Vg + base + (size_t)(32 * w + 16 * hi) * DHEAD + c;

    float4 rk[8];
    float  rv[32];

    auto load_tile = [&](int kt) {
        const float* Kp = Kpb + (size_t)kt * 128 * DHEAD;
        #pragma unroll
        for (int t = 0; t < 8; ++t) rk[t] = *(const float4*)(Kp + 4 * t);
        const float* Vp = Vpb + (size_t)kt * 128 * DHEAD;
        #pragma unroll
        for (int j = 0; j < 16; ++j) {
            rv[j]      = Vp[j * DHEAD];
            rv[16 + j] = Vp[j * DHEAD + 32];
        }
    };

    auto write_tile = [&](int nb) {
        #pragma unroll
        for (int q = 0; q < 2; ++q)
            #pragma unroll
            for (int hh = 0; hh < 2; ++hh) {
                const float4 r0 = rk[4 * q + 2 * hh], r1 = rk[4 * q + 2 * hh + 1];
                sK4[nb][w * 4 + 2 * hi + q][hh * 32 + c] =
                    make_uint4(pk2(r0.x, r0.y), pk2(r0.z, r0.w),
                               pk2(r1.x, r1.y), pk2(r1.z, r1.w));
            }
        #pragma unroll
        for (int dt = 0; dt < 2; ++dt)
            #pragma unroll
            for (int hh = 0; hh < 2; ++hh) {
                const int b = 16 * dt + 8 * hh;
                sV4[nb][(2 * w + hi) * 2 + dt][hh * 32 + c] =
                    make_uint4(pk2(rv[b + 0], rv[b + 1]), pk2(rv[b + 2], rv[b + 3]),
                               pk2(rv[b + 4], rv[b + 5]), pk2(rv[b + 6], rv[b + 7]));
            }
    };

    f32x16 o0 = {0,0,0,0,0,0,0,0,0,0,0,0,0,0,0,0};
    f32x16 o1 = o0;
    float m_r = -1e30f, l_r = 0.f;

    load_tile(0);
    write_tile(0);
    __syncthreads();

    for (int kt = 0; kt < nt; ++kt) {
        const int  cur = kt & 1;
        const bool pf  = (kt + 1 < nt);
        if (pf) load_tile(kt + 1);          // issue-early (T14)

        if (kt <= Tw) {
            const bool diag = (kt == Tw);
            const int  nkb  = diag ? nkbD : 4;

            float p[4][16];

            // ---- S^T = K * Q^T ----
            __builtin_amdgcn_s_setprio(1);
            #pragma unroll
            for (int kb = 0; kb < 4; ++kb) {
                if (kb < nkb) {
                    f32x16 s = {0,0,0,0,0,0,0,0,0,0,0,0,0,0,0,0};
                    #pragma unroll
                    for (int kc = 0; kc < 4; ++kc) {
                        U4S8 t; t.u = sK4[cur][kb * 4 + kc][lane];
                        s = __builtin_amdgcn_mfma_f32_32x32x16_bf16(t.s, qf[kc], s, 0, 0, 0);
                    }
                    #pragma unroll
                    for (int r = 0; r < 16; ++r) p[kb][r] = s[r];
                }
            }
            __builtin_amdgcn_s_setprio(0);

            // diagonal mask: compile-time kb index, runtime CONDITION only
            #pragma unroll
            for (int kb = 0; kb < 4; ++kb) {
                if (diag && kb == nkbD - 1) {
                    #pragma unroll
                    for (int r = 0; r < 16; ++r) {
                        const int kk = (r & 3) + 8 * (r >> 2) + 4 * hi;
                        if (kk > c) p[kb][r] = -1e30f;
                    }
                }
            }

            // ---- online softmax (depth-4 trees, exp2 domain) ----
            float mx = MAX16(p[0]);
            if (nkb > 1) {
                float mxb = (nkb > 2) ? fmaxf(MAX16(p[1]),
                                              (nkb > 3) ? fmaxf(MAX16(p[2]), MAX16(p[3]))
                                                        : MAX16(p[2]))
                                      : MAX16(p[1]);
                mx = fmaxf(mx, mxb);
            }
            mx = fmaxf(mx, __shfl_xor(mx, 32));

            if (__any(mx > m_r + 8.f)) {    // defer-max (T13)
                const float mn    = fmaxf(m_r, mx);
                const float alpha = fexp2(m_r - mn);
                m_r  = mn;
                l_r *= alpha;
                #pragma unroll
                for (int r = 0; r < 16; ++r) {
                    const float ab = __shfl(alpha, (r & 3) + 8 * (r >> 2) + 4 * hi);
                    o0[r] *= ab; o1[r] *= ab;
                }
            }

            #pragma unroll
            for (int kb = 0; kb < 4; ++kb) {
                if (kb < nkb) {
                    #pragma unroll
                    for (int r = 0; r < 16; ++r) p[kb][r] = fexp2(p[kb][r] - m_r);
                }
            }
            float rs = SUM16(p[0]);
            if (nkb > 1) {
                float rsb = (nkb > 2) ? ((nkb > 3) ? (SUM16(p[1]) + (SUM16(p[2]) + SUM16(p[3])))
                                                   : (SUM16(p[1]) + SUM16(p[2])))
                                      : SUM16(p[1]);
                rs += rsb;
            }
            rs += __shfl_xor(rs, 32);
            l_r += rs;

            // ---- P -> A-frags (in-register cross-half exchange) + O += P V ----
            __builtin_amdgcn_s_setprio(1);
            #pragma unroll
            for (int kc = 0; kc < 8; ++kc) {
                if (kc < 2 * nkb) {
                    const int kb = kc >> 1, bs = (kc & 1) * 8;
                    const unsigned w01 = pk2(p[kb][bs + 0], p[kb][bs + 1]);
                    const unsigned w23 = pk2(p[kb][bs + 2], p[kb][bs + 3]);
                    const unsigned w45 = pk2(p[kb][bs + 4], p[kb][bs + 5]);
                    const unsigned w67 = pk2(p[kb][bs + 6], p[kb][bs + 7]);
                    const unsigned x01 = (unsigned)__shfl_xor((int)w01, 32);
                    const unsigned x23 = (unsigned)__shfl_xor((int)w23, 32);
                    const unsigned x45 = (unsigned)__shfl_xor((int)w45, 32);
                    const unsigned x67 = (unsigned)__shfl_xor((int)w67, 32);
                    U4S8 t;
                    t.u = make_uint4(hi ? x45 : w01, hi ? x67 : w23,
                                     hi ? w45 : x01, hi ? w67 : x23);
                    U4S8 tv0; tv0.u = sV4[cur][kc * 2][lane];
                    o0 = __builtin_amdgcn_mfma_f32_32x32x16_bf16(t.s, tv0.s, o0, 0, 0, 0);
                    U4S8 tv1; tv1.u = sV4[cur][kc * 2 + 1][lane];
                    o1 = __builtin_amdgcn_mfma_f32_32x32x16_bf16(t.s, tv1.s, o1, 0, 0, 0);
                }
            }
            __builtin_amdgcn_s_setprio(0);
        }

        if (pf) write_tile(cur ^ 1);        // write-late
        __syncthreads();
    }

    // ---- epilogue: normalize, store ----
    const float linv = 1.f / l_r;
    float* Op = Og + base;
    #pragma unroll
    for (int r = 0; r < 16; ++r) {
        const int   cr  = (r & 3) + 8 * (r >> 2) + 4 * hi;
        const float lb  = __shfl(linv, cr);
        const int   row = q0w + cr;
        Op[(size_t)row * DHEAD + c]      = o0[r] * lb;
        Op[(size_t)row * DHEAD + 32 + c] = o1[r] * lb;
    }
}

extern "C" void kernel_launch(void* const* d_in, const int* in_sizes, int n_in,
                              void* d_out, int out_size, void* d_ws, size_t ws_size,
                              hipStream_t stream) {
    const float* Q = (const float*)d_in[0];
    const float* K = (const float*)d_in[1];
    const float* V = (const float*)d_in[2];
    float* O = (float*)d_out;
    fattn_kernel<<<dim3(512), dim3(256), 0, stream>>>(Q, K, V, O);
}

// Round 8
// 52.721 us; speedup vs baseline: 4.2451x; 1.5710x over previous
//
#include <hip/hip_runtime.h>
#include <hip/hip_bf16.h>

typedef __attribute__((ext_vector_type(8))) short bf16x8;
typedef __attribute__((ext_vector_type(16))) float f32x16;

#define DHEAD 64
#define L_SEQ 2048
// softmax scale 1/8 folded with log2(e): exp(x/8) == exp2(x*QSCALE)
#define QSCALE (0.125f * 1.44269504088896340736f)

union U4S8 { uint4 u; bf16x8 s; };

// Single-instruction f32x2 -> bf16x2 pack (RNE). No builtin on gfx950 (m240);
// __float22bfloat162_rn expands to ~8 scalar ops — this was ~400 extra VALU
// instrs per wave-tile across staging + P-pack.
__device__ __forceinline__ unsigned pk2(float a, float b) {
    unsigned r;
    asm("v_cvt_pk_bf16_f32 %0, %1, %2" : "=v"(r) : "v"(a), "v"(b));
    return r;
}

__device__ __forceinline__ float fexp2(float x) {
#if __has_builtin(__builtin_amdgcn_exp2f)
    return __builtin_amdgcn_exp2f(x);
#else
    return __expf(x * 0.69314718055994530942f);
#endif
}

// Depth-4 trees, constant-index only (rule #20: NO runtime indexing of p —
// rounds 5/6 proved one runtime-indexed store demotes the array to scratch).
#define MAX16(P) fmaxf(fmaxf(fmaxf(fmaxf(P[0],P[1]),fmaxf(P[2],P[3])),          \
                             fmaxf(fmaxf(P[4],P[5]),fmaxf(P[6],P[7]))),         \
                       fmaxf(fmaxf(fmaxf(P[8],P[9]),fmaxf(P[10],P[11])),        \
                             fmaxf(fmaxf(P[12],P[13]),fmaxf(P[14],P[15]))))
#define SUM16(P) ((((P[0]+P[1])+(P[2]+P[3]))+((P[4]+P[5])+(P[6]+P[7])))         \
                + (((P[8]+P[9])+(P[10]+P[11]))+((P[12]+P[13])+(P[14]+P[15]))))

// LDS layouts (per buffer, 16 chunks x 64 slots x 16B = 16KB each K and V):
//  K chunk kb*4+kc, slot l: K[kb*32+(l&31)][kc*16+8*(l>>5)+j]   (A-frag order)
//  V chunk kc*2+dt, slot l: V[kc*16+8*(l>>5)+j][dt*32+(l&31)]   (B-frag order)
// Every ds_read AND ds_write is chunk_base + lane*16B => conflict-free.

__global__ __launch_bounds__(256, 2)
void fattn_kernel(const float* __restrict__ Qg, const float* __restrict__ Kg,
                  const float* __restrict__ Vg, float* __restrict__ Og) {
    __shared__ uint4 sK4[2][16][64];
    __shared__ uint4 sV4[2][16][64];

    const int tid  = threadIdx.x;
    const int lane = tid & 63;
    const int w    = tid >> 6;     // wave -> rows 32w..32w+31 of this block's q-tile
    const int hi   = lane >> 5;
    const int c    = lane & 31;

    // Block decode (round-4 proven best): 512 blocks = 32 bh x 16 T.
    //  bh(i) == bh(i+256), T(i)+T(i+256) == 15 -> co-resident CU pair is
    //  work-balanced and shares the head. Heavy T first (LPT). 4 bh per XCD.
    const int id  = blockIdx.x;
    const int bh  = (id & 7) + 8 * ((id >> 3) & 3);
    const int u_  = id >> 5;                       // 0..15
    const int T   = (u_ < 8) ? (15 - u_) : (u_ - 8);

    const size_t base = (size_t)bh * L_SEQ * DHEAD;
    const int nt  = T + 1;               // 128-key KV tiles
    const int q0w = T * 128 + w * 32;    // this wave's q rows

    // ---- Q fragments (B-operand), scale folded ----
    bf16x8 qf[4];
    {
        const float* Qrow = Qg + base + (size_t)(q0w + c) * DHEAD;
        #pragma unroll
        for (int kc = 0; kc < 4; ++kc) {
            float4 aa = *(const float4*)(Qrow + kc * 16 + hi * 8);
            float4 bb = *(const float4*)(Qrow + kc * 16 + hi * 8 + 4);
            U4S8 t;
            t.u = make_uint4(pk2(aa.x * QSCALE, aa.y * QSCALE),
                             pk2(aa.z * QSCALE, aa.w * QSCALE),
                             pk2(bb.x * QSCALE, bb.y * QSCALE),
                             pk2(bb.z * QSCALE, bb.w * QSCALE));
            qf[kc] = t.s;
        }
    }

    // ---- staging: thread (w,hi,c) ----
    const float* Kpb = Kg + base + (size_t)(32 * w + c) * DHEAD + 32 * hi;
    const float* Vpb = Vg + base + (size_t)(32 * w + 16 * hi) * DHEAD + c;

    float4 rk[8];
    float  rv[32];

    auto load_tile = [&](int kt) {
        const float* Kp = Kpb + (size_t)kt * 128 * DHEAD;
        #pragma unroll
        for (int t = 0; t < 8; ++t) rk[t] = *(const float4*)(Kp + 4 * t);
        const float* Vp = Vpb + (size_t)kt * 128 * DHEAD;
        #pragma unroll
        for (int j = 0; j < 16; ++j) {
            rv[j]      = Vp[j * DHEAD];
            rv[16 + j] = Vp[j * DHEAD + 32];
        }
    };

    auto write_tile = [&](int nb) {
        #pragma unroll
        for (int q = 0; q < 2; ++q)
            #pragma unroll
            for (int hh = 0; hh < 2; ++hh) {
                const float4 r0 = rk[4 * q + 2 * hh], r1 = rk[4 * q + 2 * hh + 1];
                sK4[nb][w * 4 + 2 * hi + q][hh * 32 + c] =
                    make_uint4(pk2(r0.x, r0.y), pk2(r0.z, r0.w),
                               pk2(r1.x, r1.y), pk2(r1.z, r1.w));
            }
        #pragma unroll
        for (int dt = 0; dt < 2; ++dt)
            #pragma unroll
            for (int hh = 0; hh < 2; ++hh) {
                const int b = 16 * dt + 8 * hh;
                sV4[nb][(2 * w + hi) * 2 + dt][hh * 32 + c] =
                    make_uint4(pk2(rv[b + 0], rv[b + 1]), pk2(rv[b + 2], rv[b + 3]),
                               pk2(rv[b + 4], rv[b + 5]), pk2(rv[b + 6], rv[b + 7]));
            }
    };

    f32x16 o0 = {0,0,0,0,0,0,0,0,0,0,0,0,0,0,0,0};
    f32x16 o1 = o0;
    float m_r = -1e30f, l_r = 0.f;

    load_tile(0);
    write_tile(0);
    __syncthreads();

    for (int kt = 0; kt < nt; ++kt) {
        const int  cur = kt & 1;
        const bool pf  = (kt + 1 < nt);
        if (pf) load_tile(kt + 1);          // issue-early (T14)

        const bool diag = (kt == T);
        const int  nkb  = diag ? (w + 1) : 4;   // live 32-key sub-blocks this wave

        float p[4][16];

        // ---- S^T = K * Q^T ----
        __builtin_amdgcn_s_setprio(1);
        #pragma unroll
        for (int kb = 0; kb < 4; ++kb) {
            if (kb < nkb) {
                f32x16 s = {0,0,0,0,0,0,0,0,0,0,0,0,0,0,0,0};
                #pragma unroll
                for (int kc = 0; kc < 4; ++kc) {
                    U4S8 t; t.u = sK4[cur][kb * 4 + kc][lane];
                    s = __builtin_amdgcn_mfma_f32_32x32x16_bf16(t.s, qf[kc], s, 0, 0, 0);
                }
                #pragma unroll
                for (int r = 0; r < 16; ++r) p[kb][r] = s[r];
            }
        }
        __builtin_amdgcn_s_setprio(0);

        // diagonal mask: compile-time kb index, runtime CONDITION only
        #pragma unroll
        for (int kb = 0; kb < 4; ++kb) {
            if (diag && kb == w) {
                #pragma unroll
                for (int r = 0; r < 16; ++r) {
                    const int kk = (r & 3) + 8 * (r >> 2) + 4 * hi;
                    if (kk > c) p[kb][r] = -1e30f;
                }
            }
        }

        // ---- online softmax (depth-4 trees, exp2 domain) ----
        float mx = MAX16(p[0]);
        if (nkb > 1) {
            float mxb = (nkb > 2) ? fmaxf(MAX16(p[1]),
                                          (nkb > 3) ? fmaxf(MAX16(p[2]), MAX16(p[3]))
                                                    : MAX16(p[2]))
                                  : MAX16(p[1]);
            mx = fmaxf(mx, mxb);
        }
        mx = fmaxf(mx, __shfl_xor(mx, 32));

        if (__any(mx > m_r + 8.f)) {    // defer-max (T13)
            const float mn    = fmaxf(m_r, mx);
            const float alpha = fexp2(m_r - mn);
            m_r  = mn;
            l_r *= alpha;
            #pragma unroll
            for (int r = 0; r < 16; ++r) {
                const float ab = __shfl(alpha, (r & 3) + 8 * (r >> 2) + 4 * hi);
                o0[r] *= ab; o1[r] *= ab;
            }
        }

        #pragma unroll
        for (int kb = 0; kb < 4; ++kb) {
            if (kb < nkb) {
                #pragma unroll
                for (int r = 0; r < 16; ++r) p[kb][r] = fexp2(p[kb][r] - m_r);
            }
        }
        float rs = SUM16(p[0]);
        if (nkb > 1) {
            float rsb = (nkb > 2) ? ((nkb > 3) ? (SUM16(p[1]) + (SUM16(p[2]) + SUM16(p[3])))
                                               : (SUM16(p[1]) + SUM16(p[2])))
                                  : SUM16(p[1]);
            rs += rsb;
        }
        rs += __shfl_xor(rs, 32);
        l_r += rs;

        // ---- P -> A-frags via v_permlane32_swap_b32 (T12) + O += P V ----
        // swap(a,b): a' = {lo: a.lo, hi: b.lo-of-partner-half}, b' = {lo: a.hi
        // from partner, hi: b.hi} — exactly the two output words we need.
        __builtin_amdgcn_s_setprio(1);
        #pragma unroll
        for (int kc = 0; kc < 8; ++kc) {
            if (kc < 2 * nkb) {
                const int kb = kc >> 1, bs = (kc & 1) * 8;
                unsigned a0 = pk2(p[kb][bs + 0], p[kb][bs + 1]);
                unsigned a1 = pk2(p[kb][bs + 2], p[kb][bs + 3]);
                unsigned b0 = pk2(p[kb][bs + 4], p[kb][bs + 5]);
                unsigned b1 = pk2(p[kb][bs + 6], p[kb][bs + 7]);
                asm("v_permlane32_swap_b32 %0, %1" : "+v"(a0), "+v"(b0));
                asm("v_permlane32_swap_b32 %0, %1" : "+v"(a1), "+v"(b1));
                U4S8 t;
                t.u = make_uint4(a0, a1, b0, b1);
                U4S8 tv0; tv0.u = sV4[cur][kc * 2][lane];
                o0 = __builtin_amdgcn_mfma_f32_32x32x16_bf16(t.s, tv0.s, o0, 0, 0, 0);
                U4S8 tv1; tv1.u = sV4[cur][kc * 2 + 1][lane];
                o1 = __builtin_amdgcn_mfma_f32_32x32x16_bf16(t.s, tv1.s, o1, 0, 0, 0);
            }
        }
        __builtin_amdgcn_s_setprio(0);

        if (pf) write_tile(cur ^ 1);        // write-late (loads drained under compute)
        __syncthreads();
    }

    // ---- epilogue: normalize, store ----
    const float linv = 1.f / l_r;
    float* Op = Og + base;
    #pragma unroll
    for (int r = 0; r < 16; ++r) {
        const int   cr  = (r & 3) + 8 * (r >> 2) + 4 * hi;
        const float lb  = __shfl(linv, cr);
        const int   row = q0w + cr;
        Op[(size_t)row * DHEAD + c]      = o0[r] * lb;
        Op[(size_t)row * DHEAD + 32 + c] = o1[r] * lb;
    }
}

extern "C" void kernel_launch(void* const* d_in, const int* in_sizes, int n_in,
                              void* d_out, int out_size, void* d_ws, size_t ws_size,
                              hipStream_t stream) {
    const float* Q = (const float*)d_in[0];
    const float* K = (const float*)d_in[1];
    const float* V = (const float*)d_in[2];
    float* O = (float*)d_out;
    fattn_kernel<<<dim3(512), dim3(256), 0, stream>>>(Q, K, V, O);
}